// Round 19
// baseline (158.064 us; speedup 1.0000x reference)
//
#include <hip/hip_runtime.h>

#define NN 20000     // nodes per graph
#define NHALF 10000
#define NCH 16       // edge chunks per batch
#define SB 32        // scan blocks per batch
#define NBIN 625     // bins per scan block (SB*NBIN == NN)

typedef __attribute__((ext_vector_type(8))) __bf16 bf16x8;
typedef __attribute__((ext_vector_type(8))) unsigned short ushort8;
typedef __attribute__((ext_vector_type(4))) float f32x4;

__device__ __forceinline__ unsigned short f2bf(float f) {
    unsigned u = __builtin_bit_cast(unsigned, f);
    u += 0x7fff + ((u >> 16) & 1);   // round-to-nearest-even
    return (unsigned short)(u >> 16);
}
__device__ __forceinline__ float bf2f(unsigned short h) {
    unsigned u = ((unsigned)h) << 16;
    return __builtin_bit_cast(float, u);
}

// ---------------- merged prologue: hist (y=0,1) | tobf (y=2) | prep_w (y=3) --------

__global__ void k_pre(const int* __restrict__ dst, long dst_bs,
                      int* __restrict__ histc, int E, int ec,
                      const float* __restrict__ feat, unsigned short* __restrict__ fb,
                      const float* __restrict__ W1, const float* __restrict__ W2,
                      unsigned short* __restrict__ Wt1, unsigned short* __restrict__ Wt2) {
    int c = blockIdx.x, y = blockIdx.y, b = blockIdx.z;
    if (y == 2) {
        const int P = NN * 128 / 8 / NCH;
        const float* fp = feat + (size_t)b * NN * 128;
        unsigned short* op = fb + (size_t)b * NN * 128;
        for (int i = c * P + threadIdx.x; i < (c + 1) * P; i += 1024) {
            const float4* s = (const float4*)(fp + (size_t)i * 8);
            float4 v0 = s[0], v1 = s[1];
            ushort8 r;
            r[0] = f2bf(v0.x); r[1] = f2bf(v0.y); r[2] = f2bf(v0.z); r[3] = f2bf(v0.w);
            r[4] = f2bf(v1.x); r[5] = f2bf(v1.y); r[6] = f2bf(v1.z); r[7] = f2bf(v1.w);
            *(ushort8*)(op + (size_t)i * 8) = r;
        }
        return;
    }
    if (y == 3) {
        if (b == 0) {
            for (int i = c * 2048 + threadIdx.x; i < (c + 1) * 2048; i += 1024) {
                {   // W1 [128][256] -> Wt1 [256][128]
                    int k = i / 256, n = i % 256;
                    Wt1[n * 128 + k] = f2bf(W1[i]);
                }
                {   // W2 [256][128] -> Wt2 [128][256]
                    int k = i / 128, n = i % 128;
                    Wt2[n * 256 + k] = f2bf(W2[i]);
                }
            }
        }
        return;
    }
    int h = y;
    __shared__ int hist[NHALF];
    for (int i = threadIdx.x; i < NHALF; i += 1024) hist[i] = 0;
    __syncthreads();
    const int* d = dst + (size_t)b * dst_bs;
    int e0 = c * ec, e1 = min(e0 + ec, E);
    for (int e = e0 + threadIdx.x; e < e1; e += 1024) {
        int dd = d[e];
        if ((dd >= NHALF) == (h != 0)) atomicAdd(&hist[dd - h * NHALF], 1);
    }
    __syncthreads();
    int* out = histc + ((size_t)b * NCH + c) * NN + h * NHALF;
    for (int i = threadIdx.x; i < NHALF; i += 1024) out[i] = hist[i];
}

// ---------------- parallel 3-phase scan ----------------

__global__ void k_scan2a(const int* __restrict__ histc,
                         int* __restrict__ offs, long off_bs,
                         int* __restrict__ chunkbase, int* __restrict__ btot) {
    int blk = blockIdx.x, b = blockIdx.z;
    const int* hc = histc + (size_t)b * NCH * NN;
    int* cb = chunkbase + (size_t)b * NCH * NN;
    int i = blk * NBIN + threadIdx.x;
    __shared__ int sums[1024];
    int hv[NCH];
    int s = 0;
    if (threadIdx.x < NBIN) {
#pragma unroll
        for (int c = 0; c < NCH; c++) { hv[c] = hc[c * NN + i]; s += hv[c]; }
    }
    sums[threadIdx.x] = (threadIdx.x < NBIN) ? s : 0;
    __syncthreads();
    for (int d2 = 1; d2 < 1024; d2 <<= 1) {
        int x = (threadIdx.x >= d2) ? sums[threadIdx.x - d2] : 0;
        __syncthreads();
        sums[threadIdx.x] += x;
        __syncthreads();
    }
    if (threadIdx.x == 1023) btot[b * 64 + blk] = sums[1023];
    if (threadIdx.x < NBIN) {
        int run = sums[threadIdx.x] - s;
        offs[(size_t)b * off_bs + i] = run;
#pragma unroll
        for (int c = 0; c < NCH; c++) { cb[c * NN + i] = run; run += hv[c]; }
    }
}

__global__ void k_scan2b(int* __restrict__ offs, long off_bs,
                         const int* __restrict__ btot, int* __restrict__ boff, int n) {
    int b = blockIdx.z;
    __shared__ int bo[SB + 1];
    int t = threadIdx.x;
    if (t == 0) {
        int run = 0;
        for (int k = 0; k < SB; k++) { bo[k] = run; run += btot[b * 64 + k]; }
        bo[SB] = run;
    }
    __syncthreads();
    if (t < SB) boff[b * 64 + t] = bo[t];
    if (t == 0) offs[(size_t)b * off_bs + n] = bo[SB];
    for (int i = t; i < n; i += 1024)
        offs[(size_t)b * off_bs + i] += bo[i / NBIN];
}

__global__ void k_fill2(const int* __restrict__ src, long src_bs,
                        const int* __restrict__ dst, long dst_bs,
                        const int* __restrict__ chunkbase,
                        const int* __restrict__ boff,
                        unsigned short* __restrict__ elist, long el_bs,
                        int E, int ec) {
    int c = blockIdx.x, h = blockIdx.y, b = blockIdx.z;
    __shared__ int cur[NHALF];
    __shared__ int bo[16];
    if (threadIdx.x < 16) bo[threadIdx.x] = boff[b * 64 + h * 16 + threadIdx.x];
    __syncthreads();
    const int* cb = chunkbase + ((size_t)b * NCH + c) * NN + h * NHALF;
    for (int i = threadIdx.x; i < NHALF; i += 1024)
        cur[i] = cb[i] + bo[i / NBIN];
    __syncthreads();
    const int* dp = dst + (size_t)b * dst_bs;
    const int* sp = src + (size_t)b * src_bs;
    unsigned short* el = elist + (size_t)b * el_bs;
    int e0 = c * ec, e1 = min(e0 + ec, E);
    for (int e = e0 + threadIdx.x; e < e1; e += 1024) {
        int dd = dp[e];
        if ((dd >= NHALF) == (h != 0)) {
            int p = atomicAdd(&cur[dd - h * NHALF], 1);
            el[p] = (unsigned short)sp[e];
        }
    }
}

// ---------------- bf16 aggregation: 64-col strips; pass = XCD-half ----------------
// Packed accumulate: per u32 (2 bf16): lo = w<<16, hi = w&0xFFFF0000, float2 += ->
// v_pk_add_f32. ~40% fewer VALU instrs than per-element cvt+add.

template <bool BFOUT>
__global__ void k_agg(const unsigned short* __restrict__ feat, long feat_bs,
                      const int* __restrict__ offs, long off_bs,
                      const unsigned short* __restrict__ elist, long el_bs,
                      const float* __restrict__ bias,   // nullable
                      void* __restrict__ o1,
                      long out_bs, int N, int nb, int nbx) {
    int gid = blockIdx.x;
    int xcd = gid & 7;
    int b = xcd % nb;
    int grp = xcd / nb;
    int pass = grp & 1;
    int sub = grp >> 1;
    int xh = (8 / nb) >> 1;
    int nbk = (gid >> 3) * xh + sub;
    if (nbk >= nbx) return;
    int g = threadIdx.x >> 3;        // 32 node-groups per block
    int lane = threadIdx.x & 7;
    int n = nbk * 32 + g;
    if (n >= N) return;
    int col0 = pass * 64 + lane * 8;
    const unsigned short* fp = feat + (size_t)b * feat_bs + col0;
    const int* off = offs + (size_t)b * off_bs;
    const unsigned short* el = elist + (size_t)b * el_bs;
    int lo = off[n], hi = off[n + 1];
    float2 a0[4] = {}, a1[4] = {}, a2[4] = {}, a3[4] = {};
    auto acc = [&](float2* a, uint4 w) {
        const unsigned* wp = &w.x;
#pragma unroll
        for (int j = 0; j < 4; j++) {
            float flo = __builtin_bit_cast(float, wp[j] << 16);
            float fhi = __builtin_bit_cast(float, wp[j] & 0xFFFF0000u);
            a[j].x += flo;
            a[j].y += fhi;
        }
    };
    int e = lo;
    for (; e < hi && (e & 3); e++)
        acc(a0, *(const uint4*)&fp[(size_t)el[e] * 128]);
    for (; e + 8 <= hi; e += 8) {
        ushort4 i0 = *(const ushort4*)&el[e];
        ushort4 i1 = *(const ushort4*)&el[e + 4];
        uint4 v0 = *(const uint4*)&fp[(size_t)i0.x * 128];
        uint4 v1 = *(const uint4*)&fp[(size_t)i0.y * 128];
        uint4 v2 = *(const uint4*)&fp[(size_t)i0.z * 128];
        uint4 v3 = *(const uint4*)&fp[(size_t)i0.w * 128];
        uint4 v4 = *(const uint4*)&fp[(size_t)i1.x * 128];
        uint4 v5 = *(const uint4*)&fp[(size_t)i1.y * 128];
        uint4 v6 = *(const uint4*)&fp[(size_t)i1.z * 128];
        uint4 v7 = *(const uint4*)&fp[(size_t)i1.w * 128];
        acc(a0, v0); acc(a1, v1); acc(a2, v2); acc(a3, v3);
        acc(a0, v4); acc(a1, v5); acc(a2, v6); acc(a3, v7);
    }
    if (e + 4 <= hi) {
        ushort4 i0 = *(const ushort4*)&el[e];
        uint4 v0 = *(const uint4*)&fp[(size_t)i0.x * 128];
        uint4 v1 = *(const uint4*)&fp[(size_t)i0.y * 128];
        uint4 v2 = *(const uint4*)&fp[(size_t)i0.z * 128];
        uint4 v3 = *(const uint4*)&fp[(size_t)i0.w * 128];
        acc(a0, v0); acc(a1, v1); acc(a2, v2); acc(a3, v3);
        e += 4;
    }
    for (; e < hi; e++)
        acc(a0, *(const uint4*)&fp[(size_t)el[e] * 128]);
    float r[8];
#pragma unroll
    for (int j = 0; j < 4; j++) {
        r[2 * j]     = (a0[j].x + a1[j].x) + (a2[j].x + a3[j].x);
        r[2 * j + 1] = (a0[j].y + a1[j].y) + (a2[j].y + a3[j].y);
    }
    size_t oi = (size_t)b * out_bs + (size_t)n * 128 + col0;
    if (BFOUT) {
        ushort8 qh;
#pragma unroll
        for (int i = 0; i < 8; i++) qh[i] = f2bf(r[i]);
        *(ushort8*)((unsigned short*)o1 + oi) = qh;
    } else {
        float* op = (float*)o1 + oi;
        const float* bp = bias + col0;
#pragma unroll
        for (int i = 0; i < 8; i++) r[i] += bp[i];
        *(float4*)(op) = make_float4(r[0], r[1], r[2], r[3]);
        *(float4*)(op + 4) = make_float4(r[4], r[5], r[6], r[7]);
    }
}

// ---------------- FUSED MLP, W-register-resident, A-streaming ----------------

__launch_bounds__(256, 2)
__global__ void k_mlp(const unsigned short* __restrict__ A1, long A_bs,
                      const unsigned short* __restrict__ Wt1,
                      const unsigned short* __restrict__ Wt2,
                      const float* __restrict__ b1,
                      unsigned short* __restrict__ H2b, long C_bs,
                      int M, int ntiles) {
    __shared__ unsigned short HH[16 * 256];    // 8 KB H tile
    __shared__ unsigned short H2S[16 * 128];   // 4 KB H2 stage
    char* HHc = (char*)HH;
    char* H2c = (char*)H2S;
    int b = blockIdx.z;
    int w = threadIdx.x >> 6, lane = threadIdx.x & 63;
    int colg = lane & 15, kg = lane >> 4;

    bf16x8 w1f[4][4];
#pragma unroll
    for (int c = 0; c < 4; c++) {
        const unsigned short* ph = Wt1 + (size_t)(w * 64 + c * 16 + colg) * 128 + kg * 8;
#pragma unroll
        for (int ks = 0; ks < 4; ks++) w1f[c][ks] = *(const bf16x8*)(ph + ks * 32);
    }
    bf16x8 w2f[2][8];
#pragma unroll
    for (int c = 0; c < 2; c++) {
        const unsigned short* ph = Wt2 + (size_t)(w * 32 + c * 16 + colg) * 256 + kg * 8;
#pragma unroll
        for (int ks = 0; ks < 8; ks++) w2f[c][ks] = *(const bf16x8*)(ph + ks * 32);
    }
    float4 bv[4];
#pragma unroll
    for (int c = 0; c < 4; c++) bv[c] = *(const float4*)&b1[w * 64 + c * 16 + kg * 4];

    for (int t = blockIdx.x; t < ntiles; t += gridDim.x) {
        int row = t * 16 + colg;
        int rc = (row < M) ? row : M - 1;
        const unsigned short* pa = A1 + (size_t)b * A_bs + (size_t)rc * 128 + kg * 8;
        bf16x8 fa[4];
#pragma unroll
        for (int ks = 0; ks < 4; ks++) fa[ks] = *(const bf16x8*)(pa + ks * 32);

#pragma unroll
        for (int c = 0; c < 4; c++) {
            f32x4 a = (f32x4){0.f, 0.f, 0.f, 0.f};
#pragma unroll
            for (int ks = 0; ks < 4; ks++)
                a = __builtin_amdgcn_mfma_f32_16x16x32_bf16(w1f[c][ks], fa[ks], a, 0, 0, 0);
            float v[4] = {a[0] + bv[c].x, a[1] + bv[c].y, a[2] + bv[c].z, a[3] + bv[c].w};
#pragma unroll
            for (int j = 0; j < 4; j++) v[j] = fmaxf(v[j], 0.f);
            union { unsigned short u[4]; uint2 q; } qh;
#pragma unroll
            for (int j = 0; j < 4; j++) qh.u[j] = f2bf(v[j]);
            int off = (colg * 512 + w * 128 + c * 32 + kg * 8) ^ ((colg & 7) << 4);
            *(uint2*)(HHc + off) = qh.q;
        }
        __syncthreads();

        f32x4 a2[2];
        a2[0] = (f32x4){0.f, 0.f, 0.f, 0.f};
        a2[1] = (f32x4){0.f, 0.f, 0.f, 0.f};
#pragma unroll
        for (int ks2 = 0; ks2 < 8; ks2++) {
            int roff = (colg * 512 + ks2 * 64 + kg * 16) ^ ((colg & 7) << 4);
            bf16x8 fh = *(const bf16x8*)(HHc + roff);
            a2[0] = __builtin_amdgcn_mfma_f32_16x16x32_bf16(w2f[0][ks2], fh, a2[0], 0, 0, 0);
            a2[1] = __builtin_amdgcn_mfma_f32_16x16x32_bf16(w2f[1][ks2], fh, a2[1], 0, 0, 0);
        }
#pragma unroll
        for (int c = 0; c < 2; c++) {
            union { unsigned short u[4]; uint2 q; } qh;
#pragma unroll
            for (int j = 0; j < 4; j++) qh.u[j] = f2bf(a2[c][j]);
            int off = (colg * 256 + w * 64 + c * 32 + kg * 8) ^ ((colg & 7) << 4);
            *(uint2*)(H2c + off) = qh.q;
        }
        __syncthreads();

        {
            int idx = threadIdx.x;
            int r2 = idx >> 4;
            int u4 = idx & 15;
            int off = (r2 * 256 + u4 * 16) ^ ((r2 & 7) << 4);
            int grow = t * 16 + r2;
            if (grow < M) {
                uint4 v = *(const uint4*)(H2c + off);
                *(uint4*)(H2b + (size_t)b * C_bs + (size_t)grow * 128 + u4 * 8) = v;
            }
        }
    }
}

// ---------------- host ----------------

extern "C" void kernel_launch(void* const* d_in, const int* in_sizes, int n_in,
                              void* d_out, int out_size, void* d_ws, size_t ws_size,
                              hipStream_t stream) {
    const float* features = (const float*)d_in[0];  // [B,N,128]
    const int* src = (const int*)d_in[1];           // [B,E]
    const int* dst = (const int*)d_in[2];           // [B,E]
    const float* W1 = (const float*)d_in[3];        // [128,256]
    const float* b1 = (const float*)d_in[4];        // [256]
    const float* W2 = (const float*)d_in[5];        // [256,128]
    const float* b2 = (const float*)d_in[6];        // [128]
    float* out = (float*)d_out;                     // [B,N,128]

    const int B = 4;
    const int N = NN;
    const int E = in_sizes[1] / B;

    auto need = [&](int nb) -> size_t {
        size_t bf = ((size_t)nb * N * (128 + 128 + 128)) * sizeof(unsigned short);
        size_t wt = 2 * 32768 * sizeof(unsigned short);
        size_t hist2 = 2 * (size_t)nb * NCH * N * sizeof(int);
        size_t ints = (size_t)nb * (size_t)(N + 1) * sizeof(int)
                    + (size_t)nb * E * sizeof(unsigned short)
                    + (size_t)nb * 128 * sizeof(int);
        return bf + wt + hist2 + ints + 256;
    };
    int nb = (ws_size >= need(4)) ? 4 : 1;
    int npass = B / nb;
    int xh = (8 / nb) >> 1;                        // XCDs per (batch,half) for aggs

    char* p = (char*)d_ws;
    unsigned short* fb  = (unsigned short*)p; p += (size_t)nb * N * 128 * sizeof(unsigned short);
    unsigned short* A1  = (unsigned short*)p; p += (size_t)nb * N * 128 * sizeof(unsigned short);
    unsigned short* H2b = (unsigned short*)p; p += (size_t)nb * N * 128 * sizeof(unsigned short);
    unsigned short* Wt1 = (unsigned short*)p; p += 32768 * sizeof(unsigned short);
    unsigned short* Wt2 = (unsigned short*)p; p += 32768 * sizeof(unsigned short);
    int* histc = (int*)p;     p += (size_t)nb * NCH * N * sizeof(int);
    int* chunkbase = (int*)p; p += (size_t)nb * NCH * N * sizeof(int);
    int* offs = (int*)p;      p += (size_t)nb * (N + 1) * sizeof(int);
    int* btot = (int*)p;      p += (size_t)nb * 64 * sizeof(int);
    int* boff = (int*)p;      p += (size_t)nb * 64 * sizeof(int);
    unsigned short* elist = (unsigned short*)p;

    const int nbx = (N + 31) / 32;                 // node-blocks per pass
    const int ntiles = (N + 15) / 16;              // 16-row tiles per batch
    const int ec = (E + NCH - 1) / NCH;            // edges per chunk
    dim3 gPre(NCH, 4, nb);                         // y: 0,1=hist halves 2=tobf 3=prep_w
    dim3 gCsr(NCH, 2, nb);
    dim3 gAgg(8 * ((nbx + xh - 1) / xh), 1, 1);

    for (int pass = 0; pass < npass; pass++) {
        int b0 = pass * nb;
        const float* feat_p = features + (size_t)b0 * N * 128;
        const int* src_p = src + (size_t)b0 * E;
        const int* dst_p = dst + (size_t)b0 * E;
        float* out_p = out + (size_t)b0 * N * 128;

        // merged prologue: hist | features->bf16 | W prep
        k_pre<<<gPre, 1024, 0, stream>>>(dst_p, E, histc, E, ec,
                                         feat_p, fb, W1, W2, Wt1, Wt2);
        k_scan2a<<<dim3(SB, 1, nb), 1024, 0, stream>>>(histc, offs, N + 1,
                                                       chunkbase, btot);
        k_scan2b<<<dim3(1, 1, nb), 1024, 0, stream>>>(offs, N + 1, btot, boff, N);
        k_fill2<<<gCsr, 1024, 0, stream>>>(src_p, E, dst_p, E, chunkbase, boff,
                                           elist, E, E, ec);

        // conv1 aggregation (bf16 gather) -> single bf16 A1
        k_agg<true><<<gAgg, 256, 0, stream>>>(fb, (long)N * 128, offs, N + 1,
                                              elist, E, nullptr, A1, (long)N * 128,
                                              N, nb, nbx);
        // FUSED: H2b = bf16( relu(A1@W1+b1) @ W2 )   (W register-resident)
        k_mlp<<<dim3(250, 1, nb), 256, 0, stream>>>(
            A1, (long)N * 128, Wt1, Wt2, b1, H2b, (long)N * 128, N, ntiles);
        // conv2 aggregation (bf16 gather) + bias: out = segsum(H2b[src] -> dst) + b2
        k_agg<false><<<gAgg, 256, 0, stream>>>(H2b, (long)N * 128, offs, N + 1,
                                               elist, E, b2, out_p, (long)N * 128,
                                               N, nb, nbx);
    }
}

// Round 20
// 154.589 us; speedup vs baseline: 1.0225x; 1.0225x over previous
//
#include <hip/hip_runtime.h>

#define NN 20000     // nodes per graph
#define NHALF 10000
#define NCH 16       // edge chunks per batch
#define SB 32        // scan blocks per batch
#define NBIN 625     // bins per scan block (SB*NBIN == NN)

typedef __attribute__((ext_vector_type(8))) __bf16 bf16x8;
typedef __attribute__((ext_vector_type(8))) unsigned short ushort8;
typedef __attribute__((ext_vector_type(4))) float f32x4;

__device__ __forceinline__ unsigned short f2bf(float f) {
    unsigned u = __builtin_bit_cast(unsigned, f);
    u += 0x7fff + ((u >> 16) & 1);   // round-to-nearest-even
    return (unsigned short)(u >> 16);
}
__device__ __forceinline__ float bf2f(unsigned short h) {
    unsigned u = ((unsigned)h) << 16;
    return __builtin_bit_cast(float, u);
}

// ---------------- merged prologue: hist (y=0,1) | tobf (y=2) | prep_w (y=3) --------

__global__ void k_pre(const int* __restrict__ dst, long dst_bs,
                      int* __restrict__ histc, int E, int ec,
                      const float* __restrict__ feat, unsigned short* __restrict__ fb,
                      const float* __restrict__ W1, const float* __restrict__ W2,
                      unsigned short* __restrict__ Wt1, unsigned short* __restrict__ Wt2) {
    int c = blockIdx.x, y = blockIdx.y, b = blockIdx.z;
    if (y == 2) {
        const int P = NN * 128 / 8 / NCH;
        const float* fp = feat + (size_t)b * NN * 128;
        unsigned short* op = fb + (size_t)b * NN * 128;
        for (int i = c * P + threadIdx.x; i < (c + 1) * P; i += 1024) {
            const float4* s = (const float4*)(fp + (size_t)i * 8);
            float4 v0 = s[0], v1 = s[1];
            ushort8 r;
            r[0] = f2bf(v0.x); r[1] = f2bf(v0.y); r[2] = f2bf(v0.z); r[3] = f2bf(v0.w);
            r[4] = f2bf(v1.x); r[5] = f2bf(v1.y); r[6] = f2bf(v1.z); r[7] = f2bf(v1.w);
            *(ushort8*)(op + (size_t)i * 8) = r;
        }
        return;
    }
    if (y == 3) {
        if (b == 0) {
            for (int i = c * 2048 + threadIdx.x; i < (c + 1) * 2048; i += 1024) {
                {   // W1 [128][256] -> Wt1 [256][128]
                    int k = i / 256, n = i % 256;
                    Wt1[n * 128 + k] = f2bf(W1[i]);
                }
                {   // W2 [256][128] -> Wt2 [128][256]
                    int k = i / 128, n = i % 128;
                    Wt2[n * 256 + k] = f2bf(W2[i]);
                }
            }
        }
        return;
    }
    int h = y;
    __shared__ int hist[NHALF];
    for (int i = threadIdx.x; i < NHALF; i += 1024) hist[i] = 0;
    __syncthreads();
    const int* d = dst + (size_t)b * dst_bs;
    int e0 = c * ec, e1 = min(e0 + ec, E);
    for (int e = e0 + threadIdx.x; e < e1; e += 1024) {
        int dd = d[e];
        if ((dd >= NHALF) == (h != 0)) atomicAdd(&hist[dd - h * NHALF], 1);
    }
    __syncthreads();
    int* out = histc + ((size_t)b * NCH + c) * NN + h * NHALF;
    for (int i = threadIdx.x; i < NHALF; i += 1024) out[i] = hist[i];
}

// ---------------- parallel 3-phase scan ----------------

__global__ void k_scan2a(const int* __restrict__ histc,
                         int* __restrict__ offs, long off_bs,
                         int* __restrict__ chunkbase, int* __restrict__ btot) {
    int blk = blockIdx.x, b = blockIdx.z;
    const int* hc = histc + (size_t)b * NCH * NN;
    int* cb = chunkbase + (size_t)b * NCH * NN;
    int i = blk * NBIN + threadIdx.x;
    __shared__ int sums[1024];
    int hv[NCH];
    int s = 0;
    if (threadIdx.x < NBIN) {
#pragma unroll
        for (int c = 0; c < NCH; c++) { hv[c] = hc[c * NN + i]; s += hv[c]; }
    }
    sums[threadIdx.x] = (threadIdx.x < NBIN) ? s : 0;
    __syncthreads();
    for (int d2 = 1; d2 < 1024; d2 <<= 1) {
        int x = (threadIdx.x >= d2) ? sums[threadIdx.x - d2] : 0;
        __syncthreads();
        sums[threadIdx.x] += x;
        __syncthreads();
    }
    if (threadIdx.x == 1023) btot[b * 64 + blk] = sums[1023];
    if (threadIdx.x < NBIN) {
        int run = sums[threadIdx.x] - s;
        offs[(size_t)b * off_bs + i] = run;
#pragma unroll
        for (int c = 0; c < NCH; c++) { cb[c * NN + i] = run; run += hv[c]; }
    }
}

__global__ void k_scan2b(int* __restrict__ offs, long off_bs,
                         const int* __restrict__ btot, int* __restrict__ boff, int n) {
    int b = blockIdx.z;
    __shared__ int bo[SB + 1];
    int t = threadIdx.x;
    if (t == 0) {
        int run = 0;
        for (int k = 0; k < SB; k++) { bo[k] = run; run += btot[b * 64 + k]; }
        bo[SB] = run;
    }
    __syncthreads();
    if (t < SB) boff[b * 64 + t] = bo[t];
    if (t == 0) offs[(size_t)b * off_bs + n] = bo[SB];
    for (int i = t; i < n; i += 1024)
        offs[(size_t)b * off_bs + i] += bo[i / NBIN];
}

__global__ void k_fill2(const int* __restrict__ src, long src_bs,
                        const int* __restrict__ dst, long dst_bs,
                        const int* __restrict__ chunkbase,
                        const int* __restrict__ boff,
                        unsigned short* __restrict__ elist, long el_bs,
                        int E, int ec) {
    int c = blockIdx.x, h = blockIdx.y, b = blockIdx.z;
    __shared__ int cur[NHALF];
    __shared__ int bo[16];
    if (threadIdx.x < 16) bo[threadIdx.x] = boff[b * 64 + h * 16 + threadIdx.x];
    __syncthreads();
    const int* cb = chunkbase + ((size_t)b * NCH + c) * NN + h * NHALF;
    for (int i = threadIdx.x; i < NHALF; i += 1024)
        cur[i] = cb[i] + bo[i / NBIN];
    __syncthreads();
    const int* dp = dst + (size_t)b * dst_bs;
    const int* sp = src + (size_t)b * src_bs;
    unsigned short* el = elist + (size_t)b * el_bs;
    int e0 = c * ec, e1 = min(e0 + ec, E);
    for (int e = e0 + threadIdx.x; e < e1; e += 1024) {
        int dd = dp[e];
        if ((dd >= NHALF) == (h != 0)) {
            int p = atomicAdd(&cur[dd - h * NHALF], 1);
            el[p] = (unsigned short)sp[e];
        }
    }
}

// ---------------- bf16 aggregation: 64-col strips; pass = XCD-half ----------------
// Round-18 body (per-element cvt accumulate, 8-edge unroll) + explicit index
// prefetch: next iteration's 8 indices load while current gathers are in flight.

template <bool BFOUT>
__global__ void k_agg(const unsigned short* __restrict__ feat, long feat_bs,
                      const int* __restrict__ offs, long off_bs,
                      const unsigned short* __restrict__ elist, long el_bs,
                      const float* __restrict__ bias,   // nullable
                      void* __restrict__ o1,
                      long out_bs, int N, int nb, int nbx) {
    int gid = blockIdx.x;
    int xcd = gid & 7;
    int b = xcd % nb;
    int grp = xcd / nb;
    int pass = grp & 1;
    int sub = grp >> 1;
    int xh = (8 / nb) >> 1;
    int nbk = (gid >> 3) * xh + sub;
    if (nbk >= nbx) return;
    int g = threadIdx.x >> 3;        // 32 node-groups per block
    int lane = threadIdx.x & 7;
    int n = nbk * 32 + g;
    if (n >= N) return;
    int col0 = pass * 64 + lane * 8;
    const unsigned short* fp = feat + (size_t)b * feat_bs + col0;
    const int* off = offs + (size_t)b * off_bs;
    const unsigned short* el = elist + (size_t)b * el_bs;
    int lo = off[n], hi = off[n + 1];
    float a0[8] = {}, a1[8] = {}, a2[8] = {}, a3[8] = {};
    auto acc = [&](float* a, ushort8 v) {
#pragma unroll
        for (int i = 0; i < 8; i++) a[i] += bf2f(v[i]);
    };
    int e = lo;
    for (; e < hi && (e & 3); e++)
        acc(a0, *(const ushort8*)&fp[(size_t)el[e] * 128]);
    if (e + 8 <= hi) {
        ushort4 i0 = *(const ushort4*)&el[e];
        ushort4 i1 = *(const ushort4*)&el[e + 4];
        for (; e + 16 <= hi; e += 8) {
            ushort4 n0 = *(const ushort4*)&el[e + 8];     // prefetch next iter
            ushort4 n1 = *(const ushort4*)&el[e + 12];
            ushort8 v0 = *(const ushort8*)&fp[(size_t)i0.x * 128];
            ushort8 v1 = *(const ushort8*)&fp[(size_t)i0.y * 128];
            ushort8 v2 = *(const ushort8*)&fp[(size_t)i0.z * 128];
            ushort8 v3 = *(const ushort8*)&fp[(size_t)i0.w * 128];
            ushort8 v4 = *(const ushort8*)&fp[(size_t)i1.x * 128];
            ushort8 v5 = *(const ushort8*)&fp[(size_t)i1.y * 128];
            ushort8 v6 = *(const ushort8*)&fp[(size_t)i1.z * 128];
            ushort8 v7 = *(const ushort8*)&fp[(size_t)i1.w * 128];
            acc(a0, v0); acc(a1, v1); acc(a2, v2); acc(a3, v3);
            acc(a0, v4); acc(a1, v5); acc(a2, v6); acc(a3, v7);
            i0 = n0; i1 = n1;
        }
        {   // final full 8-edge iteration (indices already in registers)
            ushort8 v0 = *(const ushort8*)&fp[(size_t)i0.x * 128];
            ushort8 v1 = *(const ushort8*)&fp[(size_t)i0.y * 128];
            ushort8 v2 = *(const ushort8*)&fp[(size_t)i0.z * 128];
            ushort8 v3 = *(const ushort8*)&fp[(size_t)i0.w * 128];
            ushort8 v4 = *(const ushort8*)&fp[(size_t)i1.x * 128];
            ushort8 v5 = *(const ushort8*)&fp[(size_t)i1.y * 128];
            ushort8 v6 = *(const ushort8*)&fp[(size_t)i1.z * 128];
            ushort8 v7 = *(const ushort8*)&fp[(size_t)i1.w * 128];
            acc(a0, v0); acc(a1, v1); acc(a2, v2); acc(a3, v3);
            acc(a0, v4); acc(a1, v5); acc(a2, v6); acc(a3, v7);
            e += 8;
        }
    }
    if (e + 4 <= hi) {
        ushort4 i0 = *(const ushort4*)&el[e];
        ushort8 v0 = *(const ushort8*)&fp[(size_t)i0.x * 128];
        ushort8 v1 = *(const ushort8*)&fp[(size_t)i0.y * 128];
        ushort8 v2 = *(const ushort8*)&fp[(size_t)i0.z * 128];
        ushort8 v3 = *(const ushort8*)&fp[(size_t)i0.w * 128];
        acc(a0, v0); acc(a1, v1); acc(a2, v2); acc(a3, v3);
        e += 4;
    }
    for (; e < hi; e++)
        acc(a0, *(const ushort8*)&fp[(size_t)el[e] * 128]);
    float r[8];
#pragma unroll
    for (int i = 0; i < 8; i++) r[i] = (a0[i] + a1[i]) + (a2[i] + a3[i]);
    size_t oi = (size_t)b * out_bs + (size_t)n * 128 + col0;
    if (BFOUT) {
        ushort8 qh;
#pragma unroll
        for (int i = 0; i < 8; i++) qh[i] = f2bf(r[i]);
        *(ushort8*)((unsigned short*)o1 + oi) = qh;
    } else {
        float* op = (float*)o1 + oi;
        const float* bp = bias + col0;
#pragma unroll
        for (int i = 0; i < 8; i++) r[i] += bp[i];
        *(float4*)(op) = make_float4(r[0], r[1], r[2], r[3]);
        *(float4*)(op + 4) = make_float4(r[4], r[5], r[6], r[7]);
    }
}

// ---------------- FUSED MLP, W-register-resident, A-streaming ----------------

__launch_bounds__(256, 2)
__global__ void k_mlp(const unsigned short* __restrict__ A1, long A_bs,
                      const unsigned short* __restrict__ Wt1,
                      const unsigned short* __restrict__ Wt2,
                      const float* __restrict__ b1,
                      unsigned short* __restrict__ H2b, long C_bs,
                      int M, int ntiles) {
    __shared__ unsigned short HH[16 * 256];    // 8 KB H tile
    __shared__ unsigned short H2S[16 * 128];   // 4 KB H2 stage
    char* HHc = (char*)HH;
    char* H2c = (char*)H2S;
    int b = blockIdx.z;
    int w = threadIdx.x >> 6, lane = threadIdx.x & 63;
    int colg = lane & 15, kg = lane >> 4;

    bf16x8 w1f[4][4];
#pragma unroll
    for (int c = 0; c < 4; c++) {
        const unsigned short* ph = Wt1 + (size_t)(w * 64 + c * 16 + colg) * 128 + kg * 8;
#pragma unroll
        for (int ks = 0; ks < 4; ks++) w1f[c][ks] = *(const bf16x8*)(ph + ks * 32);
    }
    bf16x8 w2f[2][8];
#pragma unroll
    for (int c = 0; c < 2; c++) {
        const unsigned short* ph = Wt2 + (size_t)(w * 32 + c * 16 + colg) * 256 + kg * 8;
#pragma unroll
        for (int ks = 0; ks < 8; ks++) w2f[c][ks] = *(const bf16x8*)(ph + ks * 32);
    }
    float4 bv[4];
#pragma unroll
    for (int c = 0; c < 4; c++) bv[c] = *(const float4*)&b1[w * 64 + c * 16 + kg * 4];

    for (int t = blockIdx.x; t < ntiles; t += gridDim.x) {
        int row = t * 16 + colg;
        int rc = (row < M) ? row : M - 1;
        const unsigned short* pa = A1 + (size_t)b * A_bs + (size_t)rc * 128 + kg * 8;
        bf16x8 fa[4];
#pragma unroll
        for (int ks = 0; ks < 4; ks++) fa[ks] = *(const bf16x8*)(pa + ks * 32);

#pragma unroll
        for (int c = 0; c < 4; c++) {
            f32x4 a = (f32x4){0.f, 0.f, 0.f, 0.f};
#pragma unroll
            for (int ks = 0; ks < 4; ks++)
                a = __builtin_amdgcn_mfma_f32_16x16x32_bf16(w1f[c][ks], fa[ks], a, 0, 0, 0);
            float v[4] = {a[0] + bv[c].x, a[1] + bv[c].y, a[2] + bv[c].z, a[3] + bv[c].w};
#pragma unroll
            for (int j = 0; j < 4; j++) v[j] = fmaxf(v[j], 0.f);
            union { unsigned short u[4]; uint2 q; } qh;
#pragma unroll
            for (int j = 0; j < 4; j++) qh.u[j] = f2bf(v[j]);
            int off = (colg * 512 + w * 128 + c * 32 + kg * 8) ^ ((colg & 7) << 4);
            *(uint2*)(HHc + off) = qh.q;
        }
        __syncthreads();

        f32x4 a2[2];
        a2[0] = (f32x4){0.f, 0.f, 0.f, 0.f};
        a2[1] = (f32x4){0.f, 0.f, 0.f, 0.f};
#pragma unroll
        for (int ks2 = 0; ks2 < 8; ks2++) {
            int roff = (colg * 512 + ks2 * 64 + kg * 16) ^ ((colg & 7) << 4);
            bf16x8 fh = *(const bf16x8*)(HHc + roff);
            a2[0] = __builtin_amdgcn_mfma_f32_16x16x32_bf16(w2f[0][ks2], fh, a2[0], 0, 0, 0);
            a2[1] = __builtin_amdgcn_mfma_f32_16x16x32_bf16(w2f[1][ks2], fh, a2[1], 0, 0, 0);
        }
#pragma unroll
        for (int c = 0; c < 2; c++) {
            union { unsigned short u[4]; uint2 q; } qh;
#pragma unroll
            for (int j = 0; j < 4; j++) qh.u[j] = f2bf(a2[c][j]);
            int off = (colg * 256 + w * 64 + c * 32 + kg * 8) ^ ((colg & 7) << 4);
            *(uint2*)(H2c + off) = qh.q;
        }
        __syncthreads();

        {
            int idx = threadIdx.x;
            int r2 = idx >> 4;
            int u4 = idx & 15;
            int off = (r2 * 256 + u4 * 16) ^ ((r2 & 7) << 4);
            int grow = t * 16 + r2;
            if (grow < M) {
                uint4 v = *(const uint4*)(H2c + off);
                *(uint4*)(H2b + (size_t)b * C_bs + (size_t)grow * 128 + u4 * 8) = v;
            }
        }
    }
}

// ---------------- host ----------------

extern "C" void kernel_launch(void* const* d_in, const int* in_sizes, int n_in,
                              void* d_out, int out_size, void* d_ws, size_t ws_size,
                              hipStream_t stream) {
    const float* features = (const float*)d_in[0];  // [B,N,128]
    const int* src = (const int*)d_in[1];           // [B,E]
    const int* dst = (const int*)d_in[2];           // [B,E]
    const float* W1 = (const float*)d_in[3];        // [128,256]
    const float* b1 = (const float*)d_in[4];        // [256]
    const float* W2 = (const float*)d_in[5];        // [256,128]
    const float* b2 = (const float*)d_in[6];        // [128]
    float* out = (float*)d_out;                     // [B,N,128]

    const int B = 4;
    const int N = NN;
    const int E = in_sizes[1] / B;

    auto need = [&](int nb) -> size_t {
        size_t bf = ((size_t)nb * N * (128 + 128 + 128)) * sizeof(unsigned short);
        size_t wt = 2 * 32768 * sizeof(unsigned short);
        size_t hist2 = 2 * (size_t)nb * NCH * N * sizeof(int);
        size_t ints = (size_t)nb * (size_t)(N + 1) * sizeof(int)
                    + (size_t)nb * E * sizeof(unsigned short)
                    + (size_t)nb * 128 * sizeof(int);
        return bf + wt + hist2 + ints + 256;
    };
    int nb = (ws_size >= need(4)) ? 4 : 1;
    int npass = B / nb;
    int xh = (8 / nb) >> 1;                        // XCDs per (batch,half) for aggs

    char* p = (char*)d_ws;
    unsigned short* fb  = (unsigned short*)p; p += (size_t)nb * N * 128 * sizeof(unsigned short);
    unsigned short* A1  = (unsigned short*)p; p += (size_t)nb * N * 128 * sizeof(unsigned short);
    unsigned short* H2b = (unsigned short*)p; p += (size_t)nb * N * 128 * sizeof(unsigned short);
    unsigned short* Wt1 = (unsigned short*)p; p += 32768 * sizeof(unsigned short);
    unsigned short* Wt2 = (unsigned short*)p; p += 32768 * sizeof(unsigned short);
    int* histc = (int*)p;     p += (size_t)nb * NCH * N * sizeof(int);
    int* chunkbase = (int*)p; p += (size_t)nb * NCH * N * sizeof(int);
    int* offs = (int*)p;      p += (size_t)nb * (N + 1) * sizeof(int);
    int* btot = (int*)p;      p += (size_t)nb * 64 * sizeof(int);
    int* boff = (int*)p;      p += (size_t)nb * 64 * sizeof(int);
    unsigned short* elist = (unsigned short*)p;

    const int nbx = (N + 31) / 32;                 // node-blocks per pass
    const int ntiles = (N + 15) / 16;              // 16-row tiles per batch
    const int ec = (E + NCH - 1) / NCH;            // edges per chunk
    dim3 gPre(NCH, 4, nb);                         // y: 0,1=hist halves 2=tobf 3=prep_w
    dim3 gCsr(NCH, 2, nb);
    dim3 gAgg(8 * ((nbx + xh - 1) / xh), 1, 1);

    for (int pass = 0; pass < npass; pass++) {
        int b0 = pass * nb;
        const float* feat_p = features + (size_t)b0 * N * 128;
        const int* src_p = src + (size_t)b0 * E;
        const int* dst_p = dst + (size_t)b0 * E;
        float* out_p = out + (size_t)b0 * N * 128;

        // merged prologue: hist | features->bf16 | W prep
        k_pre<<<gPre, 1024, 0, stream>>>(dst_p, E, histc, E, ec,
                                         feat_p, fb, W1, W2, Wt1, Wt2);
        k_scan2a<<<dim3(SB, 1, nb), 1024, 0, stream>>>(histc, offs, N + 1,
                                                       chunkbase, btot);
        k_scan2b<<<dim3(1, 1, nb), 1024, 0, stream>>>(offs, N + 1, btot, boff, N);
        k_fill2<<<gCsr, 1024, 0, stream>>>(src_p, E, dst_p, E, chunkbase, boff,
                                           elist, E, E, ec);

        // conv1 aggregation (bf16 gather) -> single bf16 A1
        k_agg<true><<<gAgg, 256, 0, stream>>>(fb, (long)N * 128, offs, N + 1,
                                              elist, E, nullptr, A1, (long)N * 128,
                                              N, nb, nbx);
        // FUSED: H2b = bf16( relu(A1@W1+b1) @ W2 )   (W register-resident)
        k_mlp<<<dim3(250, 1, nb), 256, 0, stream>>>(
            A1, (long)N * 128, Wt1, Wt2, b1, H2b, (long)N * 128, N, ntiles);
        // conv2 aggregation (bf16 gather) + bias: out = segsum(H2b[src] -> dst) + b2
        k_agg<false><<<gAgg, 256, 0, stream>>>(H2b, (long)N * 128, offs, N + 1,
                                               elist, E, b2, out_p, (long)N * 128,
                                               N, nb, nbx);
    }
}

// Round 21
// 150.769 us; speedup vs baseline: 1.0484x; 1.0253x over previous
//
#include <hip/hip_runtime.h>

#define NN 20000     // nodes per graph
#define NHALF 10000
#define NCH 16       // edge chunks per batch
#define SB 32        // scan blocks per batch
#define NBIN 625     // bins per scan block (SB*NBIN == NN)

typedef __attribute__((ext_vector_type(8))) __bf16 bf16x8;
typedef __attribute__((ext_vector_type(8))) unsigned short ushort8;
typedef __attribute__((ext_vector_type(4))) float f32x4;

__device__ __forceinline__ unsigned short f2bf(float f) {
    unsigned u = __builtin_bit_cast(unsigned, f);
    u += 0x7fff + ((u >> 16) & 1);   // round-to-nearest-even
    return (unsigned short)(u >> 16);
}
__device__ __forceinline__ float bf2f(unsigned short h) {
    unsigned u = ((unsigned)h) << 16;
    return __builtin_bit_cast(float, u);
}

// ---------------- merged prologue: hist (y=0,1) | tobf (y=2) | prep_w (y=3) --------

__global__ void k_pre(const int* __restrict__ dst, long dst_bs,
                      int* __restrict__ histc, int E, int ec,
                      const float* __restrict__ feat, unsigned short* __restrict__ fb,
                      const float* __restrict__ W1, const float* __restrict__ W2,
                      unsigned short* __restrict__ Wt1, unsigned short* __restrict__ Wt2) {
    int c = blockIdx.x, y = blockIdx.y, b = blockIdx.z;
    if (y == 2) {
        const int P = NN * 128 / 8 / NCH;
        const float* fp = feat + (size_t)b * NN * 128;
        unsigned short* op = fb + (size_t)b * NN * 128;
        for (int i = c * P + threadIdx.x; i < (c + 1) * P; i += 1024) {
            const float4* s = (const float4*)(fp + (size_t)i * 8);
            float4 v0 = s[0], v1 = s[1];
            ushort8 r;
            r[0] = f2bf(v0.x); r[1] = f2bf(v0.y); r[2] = f2bf(v0.z); r[3] = f2bf(v0.w);
            r[4] = f2bf(v1.x); r[5] = f2bf(v1.y); r[6] = f2bf(v1.z); r[7] = f2bf(v1.w);
            *(ushort8*)(op + (size_t)i * 8) = r;
        }
        return;
    }
    if (y == 3) {
        if (b == 0) {
            for (int i = c * 2048 + threadIdx.x; i < (c + 1) * 2048; i += 1024) {
                {   // W1 [128][256] -> Wt1 [256][128]
                    int k = i / 256, n = i % 256;
                    Wt1[n * 128 + k] = f2bf(W1[i]);
                }
                {   // W2 [256][128] -> Wt2 [128][256]
                    int k = i / 128, n = i % 128;
                    Wt2[n * 256 + k] = f2bf(W2[i]);
                }
            }
        }
        return;
    }
    int h = y;
    __shared__ int hist[NHALF];
    for (int i = threadIdx.x; i < NHALF; i += 1024) hist[i] = 0;
    __syncthreads();
    const int* d = dst + (size_t)b * dst_bs;
    int e0 = c * ec, e1 = min(e0 + ec, E);
    for (int e = e0 + threadIdx.x; e < e1; e += 1024) {
        int dd = d[e];
        if ((dd >= NHALF) == (h != 0)) atomicAdd(&hist[dd - h * NHALF], 1);
    }
    __syncthreads();
    int* out = histc + ((size_t)b * NCH + c) * NN + h * NHALF;
    for (int i = threadIdx.x; i < NHALF; i += 1024) out[i] = hist[i];
}

// ---------------- parallel 3-phase scan ----------------

__global__ void k_scan2a(const int* __restrict__ histc,
                         int* __restrict__ offs, long off_bs,
                         int* __restrict__ chunkbase, int* __restrict__ btot) {
    int blk = blockIdx.x, b = blockIdx.z;
    const int* hc = histc + (size_t)b * NCH * NN;
    int* cb = chunkbase + (size_t)b * NCH * NN;
    int i = blk * NBIN + threadIdx.x;
    __shared__ int sums[1024];
    int hv[NCH];
    int s = 0;
    if (threadIdx.x < NBIN) {
#pragma unroll
        for (int c = 0; c < NCH; c++) { hv[c] = hc[c * NN + i]; s += hv[c]; }
    }
    sums[threadIdx.x] = (threadIdx.x < NBIN) ? s : 0;
    __syncthreads();
    for (int d2 = 1; d2 < 1024; d2 <<= 1) {
        int x = (threadIdx.x >= d2) ? sums[threadIdx.x - d2] : 0;
        __syncthreads();
        sums[threadIdx.x] += x;
        __syncthreads();
    }
    if (threadIdx.x == 1023) btot[b * 64 + blk] = sums[1023];
    if (threadIdx.x < NBIN) {
        int run = sums[threadIdx.x] - s;
        offs[(size_t)b * off_bs + i] = run;
#pragma unroll
        for (int c = 0; c < NCH; c++) { cb[c * NN + i] = run; run += hv[c]; }
    }
}

__global__ void k_scan2b(int* __restrict__ offs, long off_bs,
                         const int* __restrict__ btot, int* __restrict__ boff, int n) {
    int b = blockIdx.z;
    __shared__ int bo[SB + 1];
    int t = threadIdx.x;
    if (t == 0) {
        int run = 0;
        for (int k = 0; k < SB; k++) { bo[k] = run; run += btot[b * 64 + k]; }
        bo[SB] = run;
    }
    __syncthreads();
    if (t < SB) boff[b * 64 + t] = bo[t];
    if (t == 0) offs[(size_t)b * off_bs + n] = bo[SB];
    for (int i = t; i < n; i += 1024)
        offs[(size_t)b * off_bs + i] += bo[i / NBIN];
}

__global__ void k_fill2(const int* __restrict__ src, long src_bs,
                        const int* __restrict__ dst, long dst_bs,
                        const int* __restrict__ chunkbase,
                        const int* __restrict__ boff,
                        unsigned short* __restrict__ elist, long el_bs,
                        int E, int ec) {
    int c = blockIdx.x, h = blockIdx.y, b = blockIdx.z;
    __shared__ int cur[NHALF];
    __shared__ int bo[16];
    if (threadIdx.x < 16) bo[threadIdx.x] = boff[b * 64 + h * 16 + threadIdx.x];
    __syncthreads();
    const int* cb = chunkbase + ((size_t)b * NCH + c) * NN + h * NHALF;
    for (int i = threadIdx.x; i < NHALF; i += 1024)
        cur[i] = cb[i] + bo[i / NBIN];
    __syncthreads();
    const int* dp = dst + (size_t)b * dst_bs;
    const int* sp = src + (size_t)b * src_bs;
    unsigned short* el = elist + (size_t)b * el_bs;
    int e0 = c * ec, e1 = min(e0 + ec, E);
    for (int e = e0 + threadIdx.x; e < e1; e += 1024) {
        int dd = dp[e];
        if ((dd >= NHALF) == (h != 0)) {
            int p = atomicAdd(&cur[dd - h * NHALF], 1);
            el[p] = (unsigned short)sp[e];
        }
    }
}

// ---------------- bf16 aggregation: 64-col strips; pass = XCD-half ----------------
// Best measured body (round 18): per-element cvt accumulate, 8-edge unroll.

template <bool BFOUT>
__global__ void k_agg(const unsigned short* __restrict__ feat, long feat_bs,
                      const int* __restrict__ offs, long off_bs,
                      const unsigned short* __restrict__ elist, long el_bs,
                      const float* __restrict__ bias,   // nullable
                      void* __restrict__ o1,
                      long out_bs, int N, int nb, int nbx) {
    int gid = blockIdx.x;
    int xcd = gid & 7;
    int b = xcd % nb;
    int grp = xcd / nb;
    int pass = grp & 1;
    int sub = grp >> 1;
    int xh = (8 / nb) >> 1;
    int nbk = (gid >> 3) * xh + sub;
    if (nbk >= nbx) return;
    int g = threadIdx.x >> 3;        // 32 node-groups per block
    int lane = threadIdx.x & 7;
    int n = nbk * 32 + g;
    if (n >= N) return;
    int col0 = pass * 64 + lane * 8;
    const unsigned short* fp = feat + (size_t)b * feat_bs + col0;
    const int* off = offs + (size_t)b * off_bs;
    const unsigned short* el = elist + (size_t)b * el_bs;
    int lo = off[n], hi = off[n + 1];
    float a0[8] = {}, a1[8] = {}, a2[8] = {}, a3[8] = {};
    auto acc = [&](float* a, ushort8 v) {
#pragma unroll
        for (int i = 0; i < 8; i++) a[i] += bf2f(v[i]);
    };
    int e = lo;
    for (; e < hi && (e & 3); e++)
        acc(a0, *(const ushort8*)&fp[(size_t)el[e] * 128]);
    for (; e + 8 <= hi; e += 8) {
        ushort4 i0 = *(const ushort4*)&el[e];
        ushort4 i1 = *(const ushort4*)&el[e + 4];
        ushort8 v0 = *(const ushort8*)&fp[(size_t)i0.x * 128];
        ushort8 v1 = *(const ushort8*)&fp[(size_t)i0.y * 128];
        ushort8 v2 = *(const ushort8*)&fp[(size_t)i0.z * 128];
        ushort8 v3 = *(const ushort8*)&fp[(size_t)i0.w * 128];
        ushort8 v4 = *(const ushort8*)&fp[(size_t)i1.x * 128];
        ushort8 v5 = *(const ushort8*)&fp[(size_t)i1.y * 128];
        ushort8 v6 = *(const ushort8*)&fp[(size_t)i1.z * 128];
        ushort8 v7 = *(const ushort8*)&fp[(size_t)i1.w * 128];
        acc(a0, v0); acc(a1, v1); acc(a2, v2); acc(a3, v3);
        acc(a0, v4); acc(a1, v5); acc(a2, v6); acc(a3, v7);
    }
    if (e + 4 <= hi) {
        ushort4 i0 = *(const ushort4*)&el[e];
        ushort8 v0 = *(const ushort8*)&fp[(size_t)i0.x * 128];
        ushort8 v1 = *(const ushort8*)&fp[(size_t)i0.y * 128];
        ushort8 v2 = *(const ushort8*)&fp[(size_t)i0.z * 128];
        ushort8 v3 = *(const ushort8*)&fp[(size_t)i0.w * 128];
        acc(a0, v0); acc(a1, v1); acc(a2, v2); acc(a3, v3);
        e += 4;
    }
    for (; e < hi; e++)
        acc(a0, *(const ushort8*)&fp[(size_t)el[e] * 128]);
    float r[8];
#pragma unroll
    for (int i = 0; i < 8; i++) r[i] = (a0[i] + a1[i]) + (a2[i] + a3[i]);
    size_t oi = (size_t)b * out_bs + (size_t)n * 128 + col0;
    if (BFOUT) {
        ushort8 qh;
#pragma unroll
        for (int i = 0; i < 8; i++) qh[i] = f2bf(r[i]);
        *(ushort8*)((unsigned short*)o1 + oi) = qh;
    } else {
        float* op = (float*)o1 + oi;
        const float* bp = bias + col0;
#pragma unroll
        for (int i = 0; i < 8; i++) r[i] += bp[i];
        *(float4*)(op) = make_float4(r[0], r[1], r[2], r[3]);
        *(float4*)(op + 4) = make_float4(r[4], r[5], r[6], r[7]);
    }
}

// ---------------- FUSED MLP, W-register-resident, A-streaming ----------------

__launch_bounds__(256, 2)
__global__ void k_mlp(const unsigned short* __restrict__ A1, long A_bs,
                      const unsigned short* __restrict__ Wt1,
                      const unsigned short* __restrict__ Wt2,
                      const float* __restrict__ b1,
                      unsigned short* __restrict__ H2b, long C_bs,
                      int M, int ntiles) {
    __shared__ unsigned short HH[16 * 256];    // 8 KB H tile
    __shared__ unsigned short H2S[16 * 128];   // 4 KB H2 stage
    char* HHc = (char*)HH;
    char* H2c = (char*)H2S;
    int b = blockIdx.z;
    int w = threadIdx.x >> 6, lane = threadIdx.x & 63;
    int colg = lane & 15, kg = lane >> 4;

    bf16x8 w1f[4][4];
#pragma unroll
    for (int c = 0; c < 4; c++) {
        const unsigned short* ph = Wt1 + (size_t)(w * 64 + c * 16 + colg) * 128 + kg * 8;
#pragma unroll
        for (int ks = 0; ks < 4; ks++) w1f[c][ks] = *(const bf16x8*)(ph + ks * 32);
    }
    bf16x8 w2f[2][8];
#pragma unroll
    for (int c = 0; c < 2; c++) {
        const unsigned short* ph = Wt2 + (size_t)(w * 32 + c * 16 + colg) * 256 + kg * 8;
#pragma unroll
        for (int ks = 0; ks < 8; ks++) w2f[c][ks] = *(const bf16x8*)(ph + ks * 32);
    }
    float4 bv[4];
#pragma unroll
    for (int c = 0; c < 4; c++) bv[c] = *(const float4*)&b1[w * 64 + c * 16 + kg * 4];

    for (int t = blockIdx.x; t < ntiles; t += gridDim.x) {
        int row = t * 16 + colg;
        int rc = (row < M) ? row : M - 1;
        const unsigned short* pa = A1 + (size_t)b * A_bs + (size_t)rc * 128 + kg * 8;
        bf16x8 fa[4];
#pragma unroll
        for (int ks = 0; ks < 4; ks++) fa[ks] = *(const bf16x8*)(pa + ks * 32);

#pragma unroll
        for (int c = 0; c < 4; c++) {
            f32x4 a = (f32x4){0.f, 0.f, 0.f, 0.f};
#pragma unroll
            for (int ks = 0; ks < 4; ks++)
                a = __builtin_amdgcn_mfma_f32_16x16x32_bf16(w1f[c][ks], fa[ks], a, 0, 0, 0);
            float v[4] = {a[0] + bv[c].x, a[1] + bv[c].y, a[2] + bv[c].z, a[3] + bv[c].w};
#pragma unroll
            for (int j = 0; j < 4; j++) v[j] = fmaxf(v[j], 0.f);
            union { unsigned short u[4]; uint2 q; } qh;
#pragma unroll
            for (int j = 0; j < 4; j++) qh.u[j] = f2bf(v[j]);
            int off = (colg * 512 + w * 128 + c * 32 + kg * 8) ^ ((colg & 7) << 4);
            *(uint2*)(HHc + off) = qh.q;
        }
        __syncthreads();

        f32x4 a2[2];
        a2[0] = (f32x4){0.f, 0.f, 0.f, 0.f};
        a2[1] = (f32x4){0.f, 0.f, 0.f, 0.f};
#pragma unroll
        for (int ks2 = 0; ks2 < 8; ks2++) {
            int roff = (colg * 512 + ks2 * 64 + kg * 16) ^ ((colg & 7) << 4);
            bf16x8 fh = *(const bf16x8*)(HHc + roff);
            a2[0] = __builtin_amdgcn_mfma_f32_16x16x32_bf16(w2f[0][ks2], fh, a2[0], 0, 0, 0);
            a2[1] = __builtin_amdgcn_mfma_f32_16x16x32_bf16(w2f[1][ks2], fh, a2[1], 0, 0, 0);
        }
#pragma unroll
        for (int c = 0; c < 2; c++) {
            union { unsigned short u[4]; uint2 q; } qh;
#pragma unroll
            for (int j = 0; j < 4; j++) qh.u[j] = f2bf(a2[c][j]);
            int off = (colg * 256 + w * 64 + c * 32 + kg * 8) ^ ((colg & 7) << 4);
            *(uint2*)(H2c + off) = qh.q;
        }
        __syncthreads();

        {
            int idx = threadIdx.x;
            int r2 = idx >> 4;
            int u4 = idx & 15;
            int off = (r2 * 256 + u4 * 16) ^ ((r2 & 7) << 4);
            int grow = t * 16 + r2;
            if (grow < M) {
                uint4 v = *(const uint4*)(H2c + off);
                *(uint4*)(H2b + (size_t)b * C_bs + (size_t)grow * 128 + u4 * 8) = v;
            }
        }
    }
}

// ---------------- host ----------------

extern "C" void kernel_launch(void* const* d_in, const int* in_sizes, int n_in,
                              void* d_out, int out_size, void* d_ws, size_t ws_size,
                              hipStream_t stream) {
    const float* features = (const float*)d_in[0];  // [B,N,128]
    const int* src = (const int*)d_in[1];           // [B,E]
    const int* dst = (const int*)d_in[2];           // [B,E]
    const float* W1 = (const float*)d_in[3];        // [128,256]
    const float* b1 = (const float*)d_in[4];        // [256]
    const float* W2 = (const float*)d_in[5];        // [256,128]
    const float* b2 = (const float*)d_in[6];        // [128]
    float* out = (float*)d_out;                     // [B,N,128]

    const int B = 4;
    const int N = NN;
    const int E = in_sizes[1] / B;

    auto need = [&](int nb) -> size_t {
        size_t bf = ((size_t)nb * N * (128 + 128 + 128)) * sizeof(unsigned short);
        size_t wt = 2 * 32768 * sizeof(unsigned short);
        size_t hist2 = 2 * (size_t)nb * NCH * N * sizeof(int);
        size_t ints = (size_t)nb * (size_t)(N + 1) * sizeof(int)
                    + (size_t)nb * E * sizeof(unsigned short)
                    + (size_t)nb * 128 * sizeof(int);
        return bf + wt + hist2 + ints + 256;
    };
    int nb = (ws_size >= need(4)) ? 4 : 1;
    int npass = B / nb;
    int xh = (8 / nb) >> 1;                        // XCDs per (batch,half) for aggs

    char* p = (char*)d_ws;
    unsigned short* fb  = (unsigned short*)p; p += (size_t)nb * N * 128 * sizeof(unsigned short);
    unsigned short* A1  = (unsigned short*)p; p += (size_t)nb * N * 128 * sizeof(unsigned short);
    unsigned short* H2b = (unsigned short*)p; p += (size_t)nb * N * 128 * sizeof(unsigned short);
    unsigned short* Wt1 = (unsigned short*)p; p += 32768 * sizeof(unsigned short);
    unsigned short* Wt2 = (unsigned short*)p; p += 32768 * sizeof(unsigned short);
    int* histc = (int*)p;     p += (size_t)nb * NCH * N * sizeof(int);
    int* chunkbase = (int*)p; p += (size_t)nb * NCH * N * sizeof(int);
    int* offs = (int*)p;      p += (size_t)nb * (N + 1) * sizeof(int);
    int* btot = (int*)p;      p += (size_t)nb * 64 * sizeof(int);
    int* boff = (int*)p;      p += (size_t)nb * 64 * sizeof(int);
    unsigned short* elist = (unsigned short*)p;

    const int nbx = (N + 31) / 32;                 // node-blocks per pass
    const int ntiles = (N + 15) / 16;              // 16-row tiles per batch
    const int ec = (E + NCH - 1) / NCH;            // edges per chunk
    dim3 gPre(NCH, 4, nb);                         // y: 0,1=hist halves 2=tobf 3=prep_w
    dim3 gCsr(NCH, 2, nb);
    dim3 gAgg(8 * ((nbx + xh - 1) / xh), 1, 1);

    for (int pass = 0; pass < npass; pass++) {
        int b0 = pass * nb;
        const float* feat_p = features + (size_t)b0 * N * 128;
        const int* src_p = src + (size_t)b0 * E;
        const int* dst_p = dst + (size_t)b0 * E;
        float* out_p = out + (size_t)b0 * N * 128;

        // merged prologue: hist | features->bf16 | W prep
        k_pre<<<gPre, 1024, 0, stream>>>(dst_p, E, histc, E, ec,
                                         feat_p, fb, W1, W2, Wt1, Wt2);
        k_scan2a<<<dim3(SB, 1, nb), 1024, 0, stream>>>(histc, offs, N + 1,
                                                       chunkbase, btot);
        k_scan2b<<<dim3(1, 1, nb), 1024, 0, stream>>>(offs, N + 1, btot, boff, N);
        k_fill2<<<gCsr, 1024, 0, stream>>>(src_p, E, dst_p, E, chunkbase, boff,
                                           elist, E, E, ec);

        // conv1 aggregation (bf16 gather) -> single bf16 A1
        k_agg<true><<<gAgg, 256, 0, stream>>>(fb, (long)N * 128, offs, N + 1,
                                              elist, E, nullptr, A1, (long)N * 128,
                                              N, nb, nbx);
        // FUSED: H2b = bf16( relu(A1@W1+b1) @ W2 )   (W register-resident)
        k_mlp<<<dim3(250, 1, nb), 256, 0, stream>>>(
            A1, (long)N * 128, Wt1, Wt2, b1, H2b, (long)N * 128, N, ntiles);
        // conv2 aggregation (bf16 gather) + bias: out = segsum(H2b[src] -> dst) + b2
        k_agg<false><<<gAgg, 256, 0, stream>>>(H2b, (long)N * 128, offs, N + 1,
                                               elist, E, b2, out_p, (long)N * 128,
                                               N, nb, nbx);
    }
}